// Round 1
// baseline (774.900 us; speedup 1.0000x reference)
//
#include <hip/hip_runtime.h>

#define B 64
#define T 2000
#define D_MEM 512
#define D_Q 1024
#define D_ATT 128
#define C_LOC 32
#define K 31

// energy tiling: 20 chunks of 100 t's per batch -> grid(20,64)
#define CH2 100
#define NCH2 (T / CH2)          // 20
#define TPG 13                  // conv: t_local = g + 8*j, j<13
// ctx streaming: 40 chunks of 50 t's -> grid(40,64), partial layout unchanged
#define CH3 50
#define NPART (T / CH3)         // 40

// ws layout (floats) — unchanged from previous session
#define WS_PQ    0
#define WS_EXPW  (WS_PQ + B * D_ATT)     // unnormalized exp(e)  [B,T]
#define WS_SUMS  (WS_EXPW + B * T)       // per-chunk sums       [B,NCH2]
#define WS_PART  (WS_SUMS + B * NCH2)    // ctx partials         [NPART,B,D_MEM]

__device__ __forceinline__ float tanh_fast(float x) {
    float e = __expf(2.f * x);
    return 1.f - 2.f / (e + 1.f);
}

// K1: pq[b,d] = sum_i h[b,i]*Wq[i,d]. grid(B), block(512): 4 i-slices x 128 d.
__global__ __launch_bounds__(512) void pq_kernel(const float* __restrict__ h,
                                                 const float* __restrict__ Wq,
                                                 float* __restrict__ pq) {
    int b = blockIdx.x;
    int tid = threadIdx.x;
    int ty = tid >> 7;          // 0..3  (i-slice)
    int d  = tid & 127;         // 0..127
    __shared__ float sh[D_Q];
    __shared__ float red[4][D_ATT];
    const float* hb = h + (size_t)b * D_Q;
    if (tid < D_Q / 4) ((float4*)sh)[tid] = ((const float4*)hb)[tid];
    __syncthreads();
    float acc = 0.f;
    int ibeg = ty * 256;
#pragma unroll 8
    for (int i2 = 0; i2 < 256; ++i2) {
        int i = ibeg + i2;
        acc = fmaf(sh[i], Wq[(size_t)i * D_ATT + d], acc);
    }
    red[ty][d] = acc;
    __syncthreads();
    if (ty == 0)
        pq[b * D_ATT + d] = red[0][d] + red[1][d] + red[2][d] + red[3][d];
}

// K2 (was "mega" minus the context phase): per (chunk s, batch b):
// conv -> loc-proj -> energy -> exp -> chunk sum. The 262 MB `memory` stream
// is split out into ctx_kernel so it runs at full occupancy instead of being
// barrier-locked behind compute phases at 3 blocks/CU.
// LDS: 39.6 KB < 40 KB -> 4 blocks/CU (s_loc trimmed to 104 rows; rows >=104
// were only ever read for masked-out t's).
__global__ __launch_bounds__(256, 4) void energy_kernel(
    const float* __restrict__ aw, const float* __restrict__ pmem,
    const float* __restrict__ pq, const float* __restrict__ Wconv,
    const float* __restrict__ bconv, const float* __restrict__ Wloc,
    const float* __restrict__ v, float* __restrict__ expw,
    float* __restrict__ sums) {
    const int s = blockIdx.x, b = blockIdx.y;
    const int t0 = s * CH2;
    const int tid = threadIdx.x;

    __shared__ float s_aw[2][CH2 + K - 1];   // [2][130], 1040 B
    __shared__ float s_wc[2 * K * C_LOC];    // 7936 B, transposed conv weights
    __shared__ float s_loc[104][C_LOC];      // 13312 B (max valid row = 103)
    __shared__ float s_wloc[C_LOC * D_ATT];  // 16384 B
    __shared__ float s_pq[D_ATT];
    __shared__ float s_e[CH2];
    __shared__ float s_red[2];

    const int AWW = CH2 + K - 1;             // 130
    for (int j = tid; j < 2 * AWW; j += 256) {
        int i = j / AWW, o = j - i * AWW;
        int t = t0 - (K / 2) + o;
        s_aw[i][o] = (t >= 0 && t < T) ? aw[((size_t)b * 2 + i) * T + t] : 0.f;
    }
    for (int j = tid; j < C_LOC * 2 * K; j += 256) {
        int c = j / (2 * K), r = j - c * 2 * K;
        int i = r / K, k = r - i * K;
        s_wc[(i * K + k) * C_LOC + c] = Wconv[j];
    }
    for (int j = tid; j < C_LOC * D_ATT / 4; j += 256)
        ((float4*)s_wloc)[j] = ((const float4*)Wloc)[j];
    if (tid < D_ATT) s_pq[tid] = pq[b * D_ATT + tid];
    __syncthreads();

    // ---- conv: thread (g=tid>>5, c=tid&31), t_local = g + 8j, j<13 ----
    {
        int g = tid >> 5, c = tid & 31;
        float bc = bconv[c];
        float acc[TPG];
#pragma unroll
        for (int j = 0; j < TPG; ++j) acc[j] = bc;
#pragma unroll
        for (int i = 0; i < 2; ++i) {
#pragma unroll
            for (int k = 0; k < K; ++k) {
                float wv = s_wc[(i * K + k) * C_LOC + c];
#pragma unroll
                for (int j = 0; j < TPG; ++j)
                    acc[j] = fmaf(s_aw[i][g + 8 * j + k], wv, acc[j]);
            }
        }
#pragma unroll
        for (int j = 0; j < TPG; ++j) s_loc[g + 8 * j][c] = acc[j];
    }
    __syncthreads();

    // ---- energy + exp. jc=3 keeps only jj=0 (tl = g+96; jj>=1 was always
    // masked => 19% of proj FMAs removed). pmem loads hoisted before the
    // proj FMA block so global latency hides under 32xNJx4 FMAs.
    {
        int g = tid >> 5, dd = tid & 31;
        float4 pqv = ((const float4*)s_pq)[dd];
        float4 vv  = ((const float4*)v)[dd];
#pragma unroll
        for (int jc = 0; jc < 4; ++jc) {
            const int NJ = (jc == 3) ? 1 : 4;
            float4 pm[4], pl[4];
#pragma unroll
            for (int jj = 0; jj < NJ; ++jj) {
                int tl = g + 8 * (jc * 4 + jj);
                if (tl < CH2)   // uniform across the 32 dd-lanes
                    pm[jj] = ((const float4*)(pmem +
                              ((size_t)b * T + t0 + tl) * D_ATT))[dd];
                pl[jj] = make_float4(0.f, 0.f, 0.f, 0.f);
            }
#pragma unroll
            for (int c = 0; c < C_LOC; ++c) {
                float4 w = ((const float4*)s_wloc)[c * (D_ATT / 4) + dd];
#pragma unroll
                for (int jj = 0; jj < NJ; ++jj) {
                    float l = s_loc[g + 8 * (jc * 4 + jj)][c];
                    pl[jj].x = fmaf(l, w.x, pl[jj].x);
                    pl[jj].y = fmaf(l, w.y, pl[jj].y);
                    pl[jj].z = fmaf(l, w.z, pl[jj].z);
                    pl[jj].w = fmaf(l, w.w, pl[jj].w);
                }
            }
#pragma unroll
            for (int jj = 0; jj < NJ; ++jj) {
                int tl = g + 8 * (jc * 4 + jj);
                if (tl < CH2) {
                    float e = vv.x * tanh_fast(pqv.x + pl[jj].x + pm[jj].x)
                            + vv.y * tanh_fast(pqv.y + pl[jj].y + pm[jj].y)
                            + vv.z * tanh_fast(pqv.z + pl[jj].z + pm[jj].z)
                            + vv.w * tanh_fast(pqv.w + pl[jj].w + pm[jj].w);
#pragma unroll
                    for (int off = 16; off >= 1; off >>= 1)
                        e += __shfl_xor(e, off);
                    if (dd == 0) s_e[tl] = __expf(e);
                }
            }
        }
    }
    __syncthreads();

    // ---- chunk sum + stash unnormalized weights ----
    if (tid < 128) {
        float vsum = (tid < CH2) ? s_e[tid] : 0.f;
        if (tid < CH2) expw[(size_t)b * T + t0 + tid] = vsum;
        float r = vsum;
#pragma unroll
        for (int off = 32; off >= 1; off >>= 1) r += __shfl_xor(r, off);
        if ((tid & 63) == 0) s_red[tid >> 6] = r;
    }
    __syncthreads();
    if (tid == 0) sums[b * NCH2 + s] = s_red[0] + s_red[1];
}

// K3: pure `memory` streamer. grid(NPART=40, B), block(128), ~200 B LDS ->
// 8 blocks/CU resident (launch_bounds(128,4): VGPR<=128, no spill risk with
// unroll-10 float4 pipeline). Each block: 50 t's x 512 d, identical
// accumulation grouping/order as the old fused context phase (p = s*2+h),
// so partial values are bit-identical. Also emits out_w (= expw * inv,
// same arithmetic the old finalize used).
__global__ __launch_bounds__(128, 4) void ctx_kernel(
    const float* __restrict__ expw, const float* __restrict__ sums,
    const float* __restrict__ memory, float* __restrict__ partial,
    float* __restrict__ out_w) {
    const int p = blockIdx.x, b = blockIdx.y;
    const int t0 = p * CH3;
    const int tid = threadIdx.x;
    __shared__ float s_w[CH3];
    __shared__ float s_inv;
    if (tid < 64) {
        float r = (tid < NCH2) ? sums[b * NCH2 + tid] : 0.f;
#pragma unroll
        for (int off = 32; off >= 1; off >>= 1) r += __shfl_xor(r, off);
        if (tid == 0) s_inv = 1.f / r;
    }
    if (tid < CH3) s_w[tid] = expw[(size_t)b * T + t0 + tid];
    __syncthreads();
    if (tid < CH3) out_w[(size_t)b * T + t0 + tid] = s_w[tid] * s_inv;

    const float4* mem4 = (const float4*)(memory + ((size_t)b * T + t0) * D_MEM);
    float4 acc = {0.f, 0.f, 0.f, 0.f};
#pragma unroll 10
    for (int j = 0; j < CH3; ++j) {
        float wt = s_w[j];
        float4 mv = mem4[(size_t)j * (D_MEM / 4) + tid];
        acc.x = fmaf(wt, mv.x, acc.x);
        acc.y = fmaf(wt, mv.y, acc.y);
        acc.z = fmaf(wt, mv.z, acc.z);
        acc.w = fmaf(wt, mv.w, acc.w);
    }
    ((float4*)(partial + ((size_t)p * B + b) * D_MEM))[tid] = acc;
}

// K4: reduce the 40 unnormalized partials, scale by inv (same order as the
// previous finalize: partial sum first, then *inv -> identical numerics).
__global__ __launch_bounds__(128) void finalize_kernel(
    const float* __restrict__ sums, const float* __restrict__ partial,
    float* __restrict__ out_ctx) {
    int b = blockIdx.x, tid = threadIdx.x;
    __shared__ float s_inv;
    if (tid < 64) {
        float r = (tid < NCH2) ? sums[b * NCH2 + tid] : 0.f;
#pragma unroll
        for (int off = 32; off >= 1; off >>= 1) r += __shfl_xor(r, off);
        if (tid == 0) s_inv = 1.f / r;
    }
    __syncthreads();
    float inv = s_inv;
    const float4* p4 = (const float4*)partial;
    float4 acc = {0.f, 0.f, 0.f, 0.f};
#pragma unroll
    for (int p = 0; p < NPART; ++p) {
        float4 pv = p4[((size_t)p * B + b) * (D_MEM / 4) + tid];
        acc.x += pv.x; acc.y += pv.y; acc.z += pv.z; acc.w += pv.w;
    }
    acc.x *= inv; acc.y *= inv; acc.z *= inv; acc.w *= inv;
    ((float4*)(out_ctx + (size_t)b * D_MEM))[tid] = acc;
}

extern "C" void kernel_launch(void* const* d_in, const int* in_sizes, int n_in,
                              void* d_out, int out_size, void* d_ws, size_t ws_size,
                              hipStream_t stream) {
    const float* hidden = (const float*)d_in[0];   // [B,1,D_Q]
    const float* memory = (const float*)d_in[1];   // [B,T,D_MEM]
    const float* pmem   = (const float*)d_in[2];   // [B,T,D_ATT]
    const float* aw     = (const float*)d_in[3];   // [B,2,T]
    const float* Wq     = (const float*)d_in[4];   // [D_Q,D_ATT]
    const float* Wconv  = (const float*)d_in[5];   // [C_LOC,2,K]
    const float* bconv  = (const float*)d_in[6];   // [C_LOC]
    const float* Wloc   = (const float*)d_in[7];   // [C_LOC,D_ATT]
    const float* v      = (const float*)d_in[8];   // [D_ATT]

    float* out_ctx = (float*)d_out;                // [B,D_MEM]
    float* out_w   = (float*)d_out + B * D_MEM;    // [B,T]

    float* ws      = (float*)d_ws;
    float* pqp     = ws + WS_PQ;
    float* expw    = ws + WS_EXPW;
    float* sums    = ws + WS_SUMS;
    float* partial = ws + WS_PART;

    pq_kernel<<<B, 512, 0, stream>>>(hidden, Wq, pqp);
    energy_kernel<<<dim3(NCH2, B), 256, 0, stream>>>(aw, pmem, pqp, Wconv,
                                                     bconv, Wloc, v, expw, sums);
    ctx_kernel<<<dim3(NPART, B), 128, 0, stream>>>(expw, sums, memory, partial,
                                                   out_w);
    finalize_kernel<<<B, 128, 0, stream>>>(sums, partial, out_ctx);
}

// Round 2
// 743.653 us; speedup vs baseline: 1.0420x; 1.0420x over previous
//
#include <hip/hip_runtime.h>

#define B 64
#define T 2000
#define D_MEM 512
#define D_Q 1024
#define D_ATT 128
#define C_LOC 32
#define K 31

// energy tiling: 20 chunks of 100 t's per batch -> grid(20,64)
#define CH2 100
#define NCH2 (T / CH2)          // 20
#define TPG 13                  // conv: t_local = g + 8*j, j<13
// ctx streaming: 40 chunks of 50 t's -> grid(40,64), partial layout unchanged
#define CH3 50
#define NPART (T / CH3)         // 40

// ws layout (floats)
#define WS_PQ    0
#define WS_EXPW  (WS_PQ + B * D_ATT)     // unnormalized exp(e)  [B,T]
#define WS_SUMS  (WS_EXPW + B * T)       // per-chunk sums       [B,NCH2]
#define WS_PART  (WS_SUMS + B * NCH2)    // ctx partials         [NPART,B,D_MEM]

__device__ __forceinline__ float tanh_fast(float x) {
    float e = __expf(2.f * x);
    return 1.f - 2.f / (e + 1.f);
}

// K1: pq[b,d] = sum_i h[b,i]*Wq[i,d]. grid(B), block(512): 4 i-slices x 128 d.
__global__ __launch_bounds__(512) void pq_kernel(const float* __restrict__ h,
                                                 const float* __restrict__ Wq,
                                                 float* __restrict__ pq) {
    int b = blockIdx.x;
    int tid = threadIdx.x;
    int ty = tid >> 7;          // 0..3  (i-slice)
    int d  = tid & 127;         // 0..127
    __shared__ float sh[D_Q];
    __shared__ float red[4][D_ATT];
    const float* hb = h + (size_t)b * D_Q;
    if (tid < D_Q / 4) ((float4*)sh)[tid] = ((const float4*)hb)[tid];
    __syncthreads();
    float acc = 0.f;
    int ibeg = ty * 256;
#pragma unroll 8
    for (int i2 = 0; i2 < 256; ++i2) {
        int i = ibeg + i2;
        acc = fmaf(sh[i], Wq[(size_t)i * D_ATT + d], acc);
    }
    red[ty][d] = acc;
    __syncthreads();
    if (ty == 0)
        pq[b * D_ATT + d] = red[0][d] + red[1][d] + red[2][d] + red[3][d];
}

// K2: conv -> loc-proj -> energy -> exp -> chunk sum.
// R1 post-mortem: NJ=(jc==3)?1:4 gave the jj-loops a runtime trip count ->
// pm[]/pl[] runtime-indexed -> SCRATCH (518 MB spill writes + re-reads,
// 405 us). Fix: all loops have compile-time-constant trips. jc=0..2 covers
// tl = g+8*(jc*4+jj) <= 95 < 100 (no masking at all); the tl=g+96 tail is
// a separate scalar block (no arrays).
__global__ __launch_bounds__(256, 4) void energy_kernel(
    const float* __restrict__ aw, const float* __restrict__ pmem,
    const float* __restrict__ pq, const float* __restrict__ Wconv,
    const float* __restrict__ bconv, const float* __restrict__ Wloc,
    const float* __restrict__ v, float* __restrict__ expw,
    float* __restrict__ sums) {
    const int s = blockIdx.x, b = blockIdx.y;
    const int t0 = s * CH2;
    const int tid = threadIdx.x;

    __shared__ float s_aw[2][CH2 + K - 1];   // [2][130], 1040 B
    __shared__ float s_wc[2 * K * C_LOC];    // 7936 B, transposed conv weights
    __shared__ float s_loc[104][C_LOC];      // 13312 B (max valid row = 103)
    __shared__ float s_wloc[C_LOC * D_ATT];  // 16384 B
    __shared__ float s_pq[D_ATT];
    __shared__ float s_e[CH2];
    __shared__ float s_red[2];

    const int AWW = CH2 + K - 1;             // 130
    for (int j = tid; j < 2 * AWW; j += 256) {
        int i = j / AWW, o = j - i * AWW;
        int t = t0 - (K / 2) + o;
        s_aw[i][o] = (t >= 0 && t < T) ? aw[((size_t)b * 2 + i) * T + t] : 0.f;
    }
    for (int j = tid; j < C_LOC * 2 * K; j += 256) {
        int c = j / (2 * K), r = j - c * 2 * K;
        int i = r / K, k = r - i * K;
        s_wc[(i * K + k) * C_LOC + c] = Wconv[j];
    }
    for (int j = tid; j < C_LOC * D_ATT / 4; j += 256)
        ((float4*)s_wloc)[j] = ((const float4*)Wloc)[j];
    if (tid < D_ATT) s_pq[tid] = pq[b * D_ATT + tid];
    __syncthreads();

    // ---- conv: thread (g=tid>>5, c=tid&31), t_local = g + 8j, j<13 ----
    {
        int g = tid >> 5, c = tid & 31;
        float bc = bconv[c];
        float acc[TPG];
#pragma unroll
        for (int j = 0; j < TPG; ++j) acc[j] = bc;
#pragma unroll
        for (int i = 0; i < 2; ++i) {
#pragma unroll
            for (int k = 0; k < K; ++k) {
                float wv = s_wc[(i * K + k) * C_LOC + c];
#pragma unroll
                for (int j = 0; j < TPG; ++j)
                    acc[j] = fmaf(s_aw[i][g + 8 * j + k], wv, acc[j]);
            }
        }
#pragma unroll
        for (int j = 0; j < TPG; ++j) s_loc[g + 8 * j][c] = acc[j];
    }
    __syncthreads();

    // ---- energy + exp ----
    {
        int g = tid >> 5, dd = tid & 31;
        float4 pqv = ((const float4*)s_pq)[dd];
        float4 vv  = ((const float4*)v)[dd];

        // main: jc=0..2, jj=0..3 -> tl = g+8*(jc*4+jj) in [0,95]: always valid
#pragma unroll
        for (int jc = 0; jc < 3; ++jc) {
            float4 pm[4], pl[4];
#pragma unroll
            for (int jj = 0; jj < 4; ++jj) {
                int tl = g + 8 * (jc * 4 + jj);
                pm[jj] = ((const float4*)(pmem +
                          ((size_t)b * T + t0 + tl) * D_ATT))[dd];
                pl[jj] = make_float4(0.f, 0.f, 0.f, 0.f);
            }
#pragma unroll
            for (int c = 0; c < C_LOC; ++c) {
                float4 w = ((const float4*)s_wloc)[c * (D_ATT / 4) + dd];
#pragma unroll
                for (int jj = 0; jj < 4; ++jj) {
                    float l = s_loc[g + 8 * (jc * 4 + jj)][c];
                    pl[jj].x = fmaf(l, w.x, pl[jj].x);
                    pl[jj].y = fmaf(l, w.y, pl[jj].y);
                    pl[jj].z = fmaf(l, w.z, pl[jj].z);
                    pl[jj].w = fmaf(l, w.w, pl[jj].w);
                }
            }
#pragma unroll
            for (int jj = 0; jj < 4; ++jj) {
                int tl = g + 8 * (jc * 4 + jj);
                float e = vv.x * tanh_fast(pqv.x + pl[jj].x + pm[jj].x)
                        + vv.y * tanh_fast(pqv.y + pl[jj].y + pm[jj].y)
                        + vv.z * tanh_fast(pqv.z + pl[jj].z + pm[jj].z)
                        + vv.w * tanh_fast(pqv.w + pl[jj].w + pm[jj].w);
#pragma unroll
                for (int off = 16; off >= 1; off >>= 1)
                    e += __shfl_xor(e, off);
                if (dd == 0) s_e[tl] = __expf(e);
            }
        }

        // tail: tl = g+96, valid iff g<4 (wave-uniform: waves 0,1 active)
        {
            int tl = g + 96;
            if (tl < CH2) {
                float4 pm = ((const float4*)(pmem +
                             ((size_t)b * T + t0 + tl) * D_ATT))[dd];
                float4 pl = make_float4(0.f, 0.f, 0.f, 0.f);
#pragma unroll
                for (int c = 0; c < C_LOC; ++c) {
                    float4 w = ((const float4*)s_wloc)[c * (D_ATT / 4) + dd];
                    float l = s_loc[tl][c];
                    pl.x = fmaf(l, w.x, pl.x);
                    pl.y = fmaf(l, w.y, pl.y);
                    pl.z = fmaf(l, w.z, pl.z);
                    pl.w = fmaf(l, w.w, pl.w);
                }
                float e = vv.x * tanh_fast(pqv.x + pl.x + pm.x)
                        + vv.y * tanh_fast(pqv.y + pl.y + pm.y)
                        + vv.z * tanh_fast(pqv.z + pl.z + pm.z)
                        + vv.w * tanh_fast(pqv.w + pl.w + pm.w);
#pragma unroll
                for (int off = 16; off >= 1; off >>= 1)
                    e += __shfl_xor(e, off);
                if (dd == 0) s_e[tl] = __expf(e);
            }
        }
    }
    __syncthreads();

    // ---- chunk sum + stash unnormalized weights ----
    if (tid < 128) {
        float vsum = (tid < CH2) ? s_e[tid] : 0.f;
        if (tid < CH2) expw[(size_t)b * T + t0 + tid] = vsum;
        float r = vsum;
#pragma unroll
        for (int off = 32; off >= 1; off >>= 1) r += __shfl_xor(r, off);
        if ((tid & 63) == 0) s_red[tid >> 6] = r;
    }
    __syncthreads();
    if (tid == 0) sums[b * NCH2 + s] = s_red[0] + s_red[1];
}

// K3: pure `memory` streamer. grid(NPART=40, B), block(128), ~220 B LDS.
// 50 t's x 512 d per block; partial accumulation grouping identical to the
// original fused kernel (p = s*2+h) -> bit-identical numerics. Also emits
// out_w (= expw * inv).
__global__ __launch_bounds__(128, 4) void ctx_kernel(
    const float* __restrict__ expw, const float* __restrict__ sums,
    const float* __restrict__ memory, float* __restrict__ partial,
    float* __restrict__ out_w) {
    const int p = blockIdx.x, b = blockIdx.y;
    const int t0 = p * CH3;
    const int tid = threadIdx.x;
    __shared__ float s_w[CH3];
    __shared__ float s_inv;
    if (tid < 64) {
        float r = (tid < NCH2) ? sums[b * NCH2 + tid] : 0.f;
#pragma unroll
        for (int off = 32; off >= 1; off >>= 1) r += __shfl_xor(r, off);
        if (tid == 0) s_inv = 1.f / r;
    }
    if (tid < CH3) s_w[tid] = expw[(size_t)b * T + t0 + tid];
    __syncthreads();
    if (tid < CH3) out_w[(size_t)b * T + t0 + tid] = s_w[tid] * s_inv;

    const float4* mem4 = (const float4*)(memory + ((size_t)b * T + t0) * D_MEM);
    float4 acc = {0.f, 0.f, 0.f, 0.f};
#pragma unroll 10
    for (int j = 0; j < CH3; ++j) {
        float wt = s_w[j];
        float4 mv = mem4[(size_t)j * (D_MEM / 4) + tid];
        acc.x = fmaf(wt, mv.x, acc.x);
        acc.y = fmaf(wt, mv.y, acc.y);
        acc.z = fmaf(wt, mv.z, acc.z);
        acc.w = fmaf(wt, mv.w, acc.w);
    }
    ((float4*)(partial + ((size_t)p * B + b) * D_MEM))[tid] = acc;
}

// K4: reduce the 40 unnormalized partials, scale by inv (same order as the
// original finalize: partial sum first, then *inv -> identical numerics).
__global__ __launch_bounds__(128) void finalize_kernel(
    const float* __restrict__ sums, const float* __restrict__ partial,
    float* __restrict__ out_ctx) {
    int b = blockIdx.x, tid = threadIdx.x;
    __shared__ float s_inv;
    if (tid < 64) {
        float r = (tid < NCH2) ? sums[b * NCH2 + tid] : 0.f;
#pragma unroll
        for (int off = 32; off >= 1; off >>= 1) r += __shfl_xor(r, off);
        if (tid == 0) s_inv = 1.f / r;
    }
    __syncthreads();
    float inv = s_inv;
    const float4* p4 = (const float4*)partial;
    float4 acc = {0.f, 0.f, 0.f, 0.f};
#pragma unroll
    for (int p = 0; p < NPART; ++p) {
        float4 pv = p4[((size_t)p * B + b) * (D_MEM / 4) + tid];
        acc.x += pv.x; acc.y += pv.y; acc.z += pv.z; acc.w += pv.w;
    }
    acc.x *= inv; acc.y *= inv; acc.z *= inv; acc.w *= inv;
    ((float4*)(out_ctx + (size_t)b * D_MEM))[tid] = acc;
}

extern "C" void kernel_launch(void* const* d_in, const int* in_sizes, int n_in,
                              void* d_out, int out_size, void* d_ws, size_t ws_size,
                              hipStream_t stream) {
    const float* hidden = (const float*)d_in[0];   // [B,1,D_Q]
    const float* memory = (const float*)d_in[1];   // [B,T,D_MEM]
    const float* pmem   = (const float*)d_in[2];   // [B,T,D_ATT]
    const float* aw     = (const float*)d_in[3];   // [B,2,T]
    const float* Wq     = (const float*)d_in[4];   // [D_Q,D_ATT]
    const float* Wconv  = (const float*)d_in[5];   // [C_LOC,2,K]
    const float* bconv  = (const float*)d_in[6];   // [C_LOC]
    const float* Wloc   = (const float*)d_in[7];   // [C_LOC,D_ATT]
    const float* v      = (const float*)d_in[8];   // [D_ATT]

    float* out_ctx = (float*)d_out;                // [B,D_MEM]
    float* out_w   = (float*)d_out + B * D_MEM;    // [B,T]

    float* ws      = (float*)d_ws;
    float* pqp     = ws + WS_PQ;
    float* expw    = ws + WS_EXPW;
    float* sums    = ws + WS_SUMS;
    float* partial = ws + WS_PART;

    pq_kernel<<<B, 512, 0, stream>>>(hidden, Wq, pqp);
    energy_kernel<<<dim3(NCH2, B), 256, 0, stream>>>(aw, pmem, pqp, Wconv,
                                                     bconv, Wloc, v, expw, sums);
    ctx_kernel<<<dim3(NPART, B), 128, 0, stream>>>(expw, sums, memory, partial,
                                                   out_w);
    finalize_kernel<<<B, 128, 0, stream>>>(sums, partial, out_ctx);
}

// Round 3
// 455.003 us; speedup vs baseline: 1.7031x; 1.6344x over previous
//
#include <hip/hip_runtime.h>

#define B 64
#define T 2000
#define D_MEM 512
#define D_Q 1024
#define D_ATT 128
#define C_LOC 32
#define K 31

// energy tiling: 20 chunks of 100 t's per batch -> grid(20,64)
#define CH2 100
#define NCH2 (T / CH2)          // 20
// ctx streaming: 40 chunks of 50 t's -> grid(40,64)
#define CH3 50
#define NPART (T / CH3)         // 40

// ws layout (floats)
#define WS_PQ    0
#define WS_EXPW  (WS_PQ + B * D_ATT)     // unnormalized exp(e)  [B,T]
#define WS_SUMS  (WS_EXPW + B * T)       // per-chunk sums       [B,NCH2]
#define WS_PART  (WS_SUMS + B * NCH2)    // ctx partials         [NPART,B,D_MEM]

__device__ __forceinline__ float tanh_fast(float x) {
    float e = __expf(2.f * x);
    return 1.f - 2.f / (e + 1.f);
}

// K1: pq[b,d] = sum_i h[b,i]*Wq[i,d]. grid(B), block(512): 4 i-slices x 128 d.
__global__ __launch_bounds__(512) void pq_kernel(const float* __restrict__ h,
                                                 const float* __restrict__ Wq,
                                                 float* __restrict__ pq) {
    int b = blockIdx.x;
    int tid = threadIdx.x;
    int ty = tid >> 7;          // 0..3  (i-slice)
    int d  = tid & 127;         // 0..127
    __shared__ float sh[D_Q];
    __shared__ float red[4][D_ATT];
    const float* hb = h + (size_t)b * D_Q;
    if (tid < D_Q / 4) ((float4*)sh)[tid] = ((const float4*)hb)[tid];
    __syncthreads();
    float acc = 0.f;
    int ibeg = ty * 256;
#pragma unroll 8
    for (int i2 = 0; i2 < 256; ++i2) {
        int i = ibeg + i2;
        acc = fmaf(sh[i], Wq[(size_t)i * D_ATT + d], acc);
    }
    red[ty][d] = acc;
    __syncthreads();
    if (ty == 0)
        pq[b * D_ATT + d] = red[0][d] + red[1][d] + red[2][d] + red[3][d];
}

// Energy finish for one row: e = v . tanh(pq + pl + pm), 32-lane reduce, exp.
#define EFIN(PL, PM, ROW)                                                    \
    {                                                                        \
        float e = vv.x * tanh_fast(pqv.x + (PL).x + (PM).x)                  \
                + vv.y * tanh_fast(pqv.y + (PL).y + (PM).y)                  \
                + vv.z * tanh_fast(pqv.z + (PL).z + (PM).z)                  \
                + vv.w * tanh_fast(pqv.w + (PL).w + (PM).w);                 \
        e += __shfl_xor(e, 16); e += __shfl_xor(e, 8);                       \
        e += __shfl_xor(e, 4);  e += __shfl_xor(e, 2);                       \
        e += __shfl_xor(e, 1);                                               \
        if (dd == 0) s_e[ROW] = __expf(e);                                   \
    }

// K2: conv -> loc-proj -> energy -> exp -> chunk sum.
// R2 post-mortem: VGPR=64 + WRITE 501 MB proved pm[]/pl[]/acc[] arrays were
// NEVER register-promoted ("#pragma unroll" is only a hint; the unroller gave
// up and runtime-indexed arrays landed in scratch -> ~500 MB HBM round trip).
// Fix: NAMED scalars only. No per-thread arrays anywhere in this kernel.
__global__ __launch_bounds__(256, 4) void energy_kernel(
    const float* __restrict__ aw, const float* __restrict__ pmem,
    const float* __restrict__ pq, const float* __restrict__ Wconv,
    const float* __restrict__ bconv, const float* __restrict__ Wloc,
    const float* __restrict__ v, float* __restrict__ expw,
    float* __restrict__ sums) {
    const int s = blockIdx.x, b = blockIdx.y;
    const int t0 = s * CH2;
    const int tid = threadIdx.x;

    __shared__ float s_aw[2][CH2 + K - 1];   // [2][130], 1040 B
    __shared__ float s_wc[2 * K * C_LOC];    // 7936 B, transposed conv weights
    __shared__ float s_loc[104][C_LOC];      // 13312 B (max valid row = 103)
    __shared__ float s_wloc[C_LOC * D_ATT];  // 16384 B
    __shared__ float s_pq[D_ATT];
    __shared__ float s_e[CH2];
    __shared__ float s_red[2];

    const int AWW = CH2 + K - 1;             // 130
    for (int j = tid; j < 2 * AWW; j += 256) {
        int i = j / AWW, o = j - i * AWW;
        int t = t0 - (K / 2) + o;
        s_aw[i][o] = (t >= 0 && t < T) ? aw[((size_t)b * 2 + i) * T + t] : 0.f;
    }
    for (int j = tid; j < C_LOC * 2 * K; j += 256) {
        int c = j / (2 * K), r = j - c * 2 * K;
        int i = r / K, k = r - i * K;
        s_wc[(i * K + k) * C_LOC + c] = Wconv[j];
    }
    for (int j = tid; j < C_LOC * D_ATT / 4; j += 256)
        ((float4*)s_wloc)[j] = ((const float4*)Wloc)[j];
    if (tid < D_ATT) s_pq[tid] = pq[b * D_ATT + tid];
    __syncthreads();

    // ---- conv: thread (g=tid>>5, c=tid&31), rows g+8j, j=0..12 ----
    // 13 NAMED accumulators; i/k stay rolled loops (scalars live in VGPRs).
    // Per-row accumulation order identical to previous versions.
    {
        int g = tid >> 5, c = tid & 31;
        float bc = bconv[c];
        float a0 = bc, a1 = bc, a2 = bc, a3 = bc, a4 = bc, a5 = bc, a6 = bc,
              a7 = bc, a8 = bc, a9 = bc, a10 = bc, a11 = bc, a12 = bc;
        for (int i = 0; i < 2; ++i) {
#pragma unroll 4
            for (int k = 0; k < K; ++k) {
                float wv = s_wc[(i * K + k) * C_LOC + c];
                const float* sa = &s_aw[i][g + k];
                a0  = fmaf(sa[0],  wv, a0);
                a1  = fmaf(sa[8],  wv, a1);
                a2  = fmaf(sa[16], wv, a2);
                a3  = fmaf(sa[24], wv, a3);
                a4  = fmaf(sa[32], wv, a4);
                a5  = fmaf(sa[40], wv, a5);
                a6  = fmaf(sa[48], wv, a6);
                a7  = fmaf(sa[56], wv, a7);
                a8  = fmaf(sa[64], wv, a8);
                a9  = fmaf(sa[72], wv, a9);
                a10 = fmaf(sa[80], wv, a10);
                a11 = fmaf(sa[88], wv, a11);
                a12 = fmaf(sa[96], wv, a12);
            }
        }
        s_loc[g +  0][c] = a0;  s_loc[g +  8][c] = a1;
        s_loc[g + 16][c] = a2;  s_loc[g + 24][c] = a3;
        s_loc[g + 32][c] = a4;  s_loc[g + 40][c] = a5;
        s_loc[g + 48][c] = a6;  s_loc[g + 56][c] = a7;
        s_loc[g + 64][c] = a8;  s_loc[g + 72][c] = a9;
        s_loc[g + 80][c] = a10; s_loc[g + 88][c] = a11;
        s_loc[g + 96][c] = a12;
    }
    __syncthreads();

    // ---- energy + exp: 3 groups of 4 rows (named float4s), then tail ----
    {
        int g = tid >> 5, dd = tid & 31;
        float4 pqv = ((const float4*)s_pq)[dd];
        float4 vv  = ((const float4*)v)[dd];
        const float4* pmb =
            (const float4*)(pmem + ((size_t)b * T + t0) * D_ATT);

        for (int jc = 0; jc < 3; ++jc) {
            int r0 = g + 32 * jc;            // rows r0, r0+8, r0+16, r0+24 <= 95
            // pm loads issue here; latency hides under the 512-FMA c-loop
            float4 pm0 = pmb[(size_t)(r0)      * (D_ATT / 4) + dd];
            float4 pm1 = pmb[(size_t)(r0 +  8) * (D_ATT / 4) + dd];
            float4 pm2 = pmb[(size_t)(r0 + 16) * (D_ATT / 4) + dd];
            float4 pm3 = pmb[(size_t)(r0 + 24) * (D_ATT / 4) + dd];
            float4 pl0 = make_float4(0.f, 0.f, 0.f, 0.f);
            float4 pl1 = make_float4(0.f, 0.f, 0.f, 0.f);
            float4 pl2 = make_float4(0.f, 0.f, 0.f, 0.f);
            float4 pl3 = make_float4(0.f, 0.f, 0.f, 0.f);
#pragma unroll 4
            for (int c = 0; c < C_LOC; ++c) {
                float4 w = ((const float4*)s_wloc)[c * (D_ATT / 4) + dd];
                float l0 = s_loc[r0][c];
                float l1 = s_loc[r0 + 8][c];
                float l2 = s_loc[r0 + 16][c];
                float l3 = s_loc[r0 + 24][c];
                pl0.x = fmaf(l0, w.x, pl0.x); pl0.y = fmaf(l0, w.y, pl0.y);
                pl0.z = fmaf(l0, w.z, pl0.z); pl0.w = fmaf(l0, w.w, pl0.w);
                pl1.x = fmaf(l1, w.x, pl1.x); pl1.y = fmaf(l1, w.y, pl1.y);
                pl1.z = fmaf(l1, w.z, pl1.z); pl1.w = fmaf(l1, w.w, pl1.w);
                pl2.x = fmaf(l2, w.x, pl2.x); pl2.y = fmaf(l2, w.y, pl2.y);
                pl2.z = fmaf(l2, w.z, pl2.z); pl2.w = fmaf(l2, w.w, pl2.w);
                pl3.x = fmaf(l3, w.x, pl3.x); pl3.y = fmaf(l3, w.y, pl3.y);
                pl3.z = fmaf(l3, w.z, pl3.z); pl3.w = fmaf(l3, w.w, pl3.w);
            }
            EFIN(pl0, pm0, r0);
            EFIN(pl1, pm1, r0 + 8);
            EFIN(pl2, pm2, r0 + 16);
            EFIN(pl3, pm3, r0 + 24);
        }

        // tail: row g+96, valid iff g<4 (uniform across the 32 dd-lanes)
        {
            int tl = g + 96;
            if (tl < CH2) {
                float4 pm = pmb[(size_t)tl * (D_ATT / 4) + dd];
                float4 pl = make_float4(0.f, 0.f, 0.f, 0.f);
#pragma unroll 4
                for (int c = 0; c < C_LOC; ++c) {
                    float4 w = ((const float4*)s_wloc)[c * (D_ATT / 4) + dd];
                    float l = s_loc[tl][c];
                    pl.x = fmaf(l, w.x, pl.x);
                    pl.y = fmaf(l, w.y, pl.y);
                    pl.z = fmaf(l, w.z, pl.z);
                    pl.w = fmaf(l, w.w, pl.w);
                }
                EFIN(pl, pm, tl);
            }
        }
    }
    __syncthreads();

    // ---- chunk sum + stash unnormalized weights ----
    if (tid < 128) {
        float vsum = (tid < CH2) ? s_e[tid] : 0.f;
        if (tid < CH2) expw[(size_t)b * T + t0 + tid] = vsum;
        float r = vsum;
#pragma unroll
        for (int off = 32; off >= 1; off >>= 1) r += __shfl_xor(r, off);
        if ((tid & 63) == 0) s_red[tid >> 6] = r;
    }
    __syncthreads();
    if (tid == 0) sums[b * NCH2 + s] = s_red[0] + s_red[1];
}

// K3: pure `memory` streamer. grid(NPART=40, B), block(128).
// Partial accumulation grouping identical to the original fused kernel
// (p = s*2+h) -> bit-identical numerics. Also emits out_w (= expw * inv).
__global__ __launch_bounds__(128, 4) void ctx_kernel(
    const float* __restrict__ expw, const float* __restrict__ sums,
    const float* __restrict__ memory, float* __restrict__ partial,
    float* __restrict__ out_w) {
    const int p = blockIdx.x, b = blockIdx.y;
    const int t0 = p * CH3;
    const int tid = threadIdx.x;
    __shared__ float s_w[CH3];
    __shared__ float s_inv;
    if (tid < 64) {
        float r = (tid < NCH2) ? sums[b * NCH2 + tid] : 0.f;
#pragma unroll
        for (int off = 32; off >= 1; off >>= 1) r += __shfl_xor(r, off);
        if (tid == 0) s_inv = 1.f / r;
    }
    if (tid < CH3) s_w[tid] = expw[(size_t)b * T + t0 + tid];
    __syncthreads();
    if (tid < CH3) out_w[(size_t)b * T + t0 + tid] = s_w[tid] * s_inv;

    const float4* mem4 = (const float4*)(memory + ((size_t)b * T + t0) * D_MEM);
    float4 acc = {0.f, 0.f, 0.f, 0.f};
#pragma unroll 10
    for (int j = 0; j < CH3; ++j) {
        float wt = s_w[j];
        float4 mv = mem4[(size_t)j * (D_MEM / 4) + tid];
        acc.x = fmaf(wt, mv.x, acc.x);
        acc.y = fmaf(wt, mv.y, acc.y);
        acc.z = fmaf(wt, mv.z, acc.z);
        acc.w = fmaf(wt, mv.w, acc.w);
    }
    ((float4*)(partial + ((size_t)p * B + b) * D_MEM))[tid] = acc;
}

// K4: reduce the 40 unnormalized partials, scale by inv (same order as the
// original finalize: partial sum first, then *inv -> identical numerics).
__global__ __launch_bounds__(128) void finalize_kernel(
    const float* __restrict__ sums, const float* __restrict__ partial,
    float* __restrict__ out_ctx) {
    int b = blockIdx.x, tid = threadIdx.x;
    __shared__ float s_inv;
    if (tid < 64) {
        float r = (tid < NCH2) ? sums[b * NCH2 + tid] : 0.f;
#pragma unroll
        for (int off = 32; off >= 1; off >>= 1) r += __shfl_xor(r, off);
        if (tid == 0) s_inv = 1.f / r;
    }
    __syncthreads();
    float inv = s_inv;
    const float4* p4 = (const float4*)partial;
    float4 acc = {0.f, 0.f, 0.f, 0.f};
#pragma unroll
    for (int p = 0; p < NPART; ++p) {
        float4 pv = p4[((size_t)p * B + b) * (D_MEM / 4) + tid];
        acc.x += pv.x; acc.y += pv.y; acc.z += pv.z; acc.w += pv.w;
    }
    acc.x *= inv; acc.y *= inv; acc.z *= inv; acc.w *= inv;
    ((float4*)(out_ctx + (size_t)b * D_MEM))[tid] = acc;
}

extern "C" void kernel_launch(void* const* d_in, const int* in_sizes, int n_in,
                              void* d_out, int out_size, void* d_ws, size_t ws_size,
                              hipStream_t stream) {
    const float* hidden = (const float*)d_in[0];   // [B,1,D_Q]
    const float* memory = (const float*)d_in[1];   // [B,T,D_MEM]
    const float* pmem   = (const float*)d_in[2];   // [B,T,D_ATT]
    const float* aw     = (const float*)d_in[3];   // [B,2,T]
    const float* Wq     = (const float*)d_in[4];   // [D_Q,D_ATT]
    const float* Wconv  = (const float*)d_in[5];   // [C_LOC,2,K]
    const float* bconv  = (const float*)d_in[6];   // [C_LOC]
    const float* Wloc   = (const float*)d_in[7];   // [C_LOC,D_ATT]
    const float* v      = (const float*)d_in[8];   // [D_ATT]

    float* out_ctx = (float*)d_out;                // [B,D_MEM]
    float* out_w   = (float*)d_out + B * D_MEM;    // [B,T]

    float* ws      = (float*)d_ws;
    float* pqp     = ws + WS_PQ;
    float* expw    = ws + WS_EXPW;
    float* sums    = ws + WS_SUMS;
    float* partial = ws + WS_PART;

    pq_kernel<<<B, 512, 0, stream>>>(hidden, Wq, pqp);
    energy_kernel<<<dim3(NCH2, B), 256, 0, stream>>>(aw, pmem, pqp, Wconv,
                                                     bconv, Wloc, v, expw, sums);
    ctx_kernel<<<dim3(NPART, B), 128, 0, stream>>>(expw, sums, memory, partial,
                                                   out_w);
    finalize_kernel<<<B, 128, 0, stream>>>(sums, partial, out_ctx);
}